// Round 11
// baseline (232.450 us; speedup 1.0000x reference)
//
#include <hip/hip_runtime.h>
#include <cstdint>
#include <cstddef>

#define BQ 16
#define NT 1024
#define CH 768
#define HIDN 128
#define OUTF 2304
#define MTOT (BQ*NT)   // 16384 tokens

typedef __attribute__((ext_vector_type(4))) float f32x4;
typedef __attribute__((ext_vector_type(8))) short short8;   // 8 x bf16 payload

// ---------- small helpers ----------
__device__ __forceinline__ unsigned short f2bf(float f){
  unsigned u = __float_as_uint(f);
  u += 0x7FFFu + ((u >> 16) & 1u);      // RNE
  return (unsigned short)(u >> 16);
}
__device__ __forceinline__ float bf2f(unsigned short h){
  return __uint_as_float(((unsigned)h) << 16);
}

__device__ __forceinline__ void gload16(const void* g, void* l){
  __builtin_amdgcn_global_load_lds((const __attribute__((address_space(1))) void*)g,
                                   (__attribute__((address_space(3))) void*)l, 16, 0, 0);
}

__device__ __forceinline__ void mfma16(f32x4& d, short8 a, short8 b){
  asm volatile("v_mfma_f32_16x16x32_bf16 %0, %1, %2, %0" : "+v"(d) : "v"(a), "v"(b));
}

__device__ __forceinline__ short8 pack8(float4 a, float4 b){
  short8 p;
  p[0]=(short)f2bf(a.x); p[1]=(short)f2bf(a.y); p[2]=(short)f2bf(a.z); p[3]=(short)f2bf(a.w);
  p[4]=(short)f2bf(b.x); p[5]=(short)f2bf(b.y); p[6]=(short)f2bf(b.z); p[7]=(short)f2bf(b.w);
  return p;
}

// ============================================================================
// 256x256 8-phase GEMM body (T1+T2+T3+T4+T5) — r3/r5/r7/r9/r10-validated
// ============================================================================
#define STAGE(matB_, buf_, h_, t_) { \
    const unsigned short* g_ = ((matB_) ? Bbase : Abase) + (size_t)(h_)*128*K + (size_t)(t_)*64; \
    char* d_ = ldsWaveDst + (matB_)*65536 + (buf_)*32768 + (h_)*16384; \
    gload16(g_, d_); \
    gload16(g_ + rowK64, d_ + 8192); \
  }

#define PH_OPEN() \
    asm volatile("s_barrier" ::: "memory"); \
    asm volatile("s_waitcnt lgkmcnt(0)" ::: "memory"); \
    __builtin_amdgcn_sched_barrier(0); \
    __builtin_amdgcn_s_setprio(1);

#define PH_CLOSE() \
    __builtin_amdgcn_s_setprio(0); \
    asm volatile("s_barrier" ::: "memory");

#define MF16(mb, nb, BV) \
    _Pragma("unroll") \
    for (int ks = 0; ks < 2; ++ks) \
      _Pragma("unroll") \
      for (int mf = 0; mf < 4; ++mf) \
        _Pragma("unroll") \
        for (int nf = 0; nf < 2; ++nf) \
          mfma16(acc[(mb)+mf][(nb)+nf], av[mf][ks], BV[nf][ks]);

#define TILE(t_, b_) { \
    const int t = (t_); const int b = (b_); \
    _Pragma("unroll") for (int mf = 0; mf < 4; ++mf){ av[mf][0]=ldA(b,mf,0); av[mf][1]=ldA(b,mf,1); } \
    _Pragma("unroll") for (int nf = 0; nf < 2; ++nf){ b0v[nf][0]=ldB(b,nf,0); b0v[nf][1]=ldB(b,nf,1); } \
    if (t+1 < T) STAGE(0, b^1, 1, t+1); \
    PH_OPEN(); MF16(0,0,b0v); PH_CLOSE(); \
    _Pragma("unroll") for (int nf = 0; nf < 2; ++nf){ b1v[nf][0]=ldB(b,2+nf,0); b1v[nf][1]=ldB(b,2+nf,1); } \
    if (t+1 < T) STAGE(1, b^1, 0, t+1); \
    PH_OPEN(); MF16(0,2,b1v); PH_CLOSE(); \
    _Pragma("unroll") for (int mf = 0; mf < 4; ++mf){ av[mf][0]=ldA(b,4+mf,0); av[mf][1]=ldA(b,4+mf,1); } \
    if (t+2 < T) STAGE(0, b, 0, t+2); \
    PH_OPEN(); MF16(4,2,b1v); PH_CLOSE(); \
    if (t+2 < T) STAGE(1, b, 1, t+2); \
    PH_OPEN(); MF16(4,0,b0v); \
    __builtin_amdgcn_s_setprio(0); \
    if (t+2 < T) { asm volatile("s_waitcnt vmcnt(4)" ::: "memory"); } \
    else         { asm volatile("s_waitcnt vmcnt(0)" ::: "memory"); } \
    asm volatile("s_barrier" ::: "memory"); \
  }

template<int T>   // K = T*64, T even
__device__ __forceinline__
void gemm256_body(char* lds8,
                  const unsigned short* __restrict__ A,
                  const unsigned short* __restrict__ B,
                  const float* __restrict__ bias,
                  float* __restrict__ C,
                  int N, int K, int nbn, int bid, int nwg)
{
  const int tid = threadIdx.x;
  const int ln = tid & 63, wv = tid >> 6;
  const int wm = wv >> 2, wn = wv & 3;
  const int llo = ln & 15, lhi = ln >> 4;

  const int cpx = nwg >> 3;
  const int swz = (bid & 7) * cpx + (bid >> 3);
  const int bm = swz / nbn, bn = swz % nbn;
  const int m0 = bm * 256, n0 = bn * 256;

  const int srow = tid >> 3;
  const int sslot = (tid & 7) ^ (srow & 7);
  const unsigned short* Abase = A + (size_t)(m0 + srow) * K + sslot * 8;
  const unsigned short* Bbase = B + (size_t)(n0 + srow) * K + sslot * 8;
  const size_t rowK64 = (size_t)64 * K;
  char* ldsWaveDst = lds8 + (wv << 10);

  const int swz0 = ((lhi ^ (ln & 7)) << 4);
  const char* aRd0 = lds8 + (wm*64 + llo)*128 + swz0;
  const char* aRd1 = lds8 + (wm*64 + llo)*128 + (swz0 ^ 64);
  const char* bRd0 = lds8 + 65536 + (wn*32 + llo)*128 + swz0;
  const char* bRd1 = lds8 + 65536 + (wn*32 + llo)*128 + (swz0 ^ 64);

  auto ldA = [&](int b, int mf, int ks) -> short8 {
    const char* p = (ks ? aRd1 : aRd0) + b*32768 + (mf>>2)*16384 + (mf&3)*2048;
    return *reinterpret_cast<const short8*>(p);
  };
  auto ldB = [&](int b, int nf, int ks) -> short8 {
    const char* p = (ks ? bRd1 : bRd0) + b*32768 + (nf>>1)*16384 + (nf&1)*2048;
    return *reinterpret_cast<const short8*>(p);
  };

  f32x4 acc[8][4];
  #pragma unroll
  for (int m = 0; m < 8; ++m)
    #pragma unroll
    for (int n = 0; n < 4; ++n) acc[m][n] = 0.0f;

  STAGE(0, 0, 0, 0);
  STAGE(1, 0, 1, 0);
  STAGE(0, 0, 1, 0);
  STAGE(1, 0, 0, 0);
  STAGE(0, 1, 0, 1);
  STAGE(1, 1, 1, 1);
  asm volatile("s_waitcnt vmcnt(4)" ::: "memory");
  asm volatile("s_barrier" ::: "memory");

  short8 av[4][2], b0v[2][2], b1v[2][2];
  #pragma unroll 1
  for (int t0 = 0; t0 < T; t0 += 2){
    TILE(t0,   0);
    TILE(t0+1, 1);
  }

  asm volatile("s_nop 7\n\ts_nop 7\n\ts_nop 7" ::: );

  #pragma unroll
  for (int mf = 0; mf < 8; ++mf){
    const int row = m0 + (mf>>2)*128 + wm*64 + (mf&3)*16 + lhi*4;
    #pragma unroll
    for (int j = 0; j < 4; ++j){
      #pragma unroll
      for (int nf = 0; nf < 4; ++nf){
        const int col = n0 + (nf>>1)*128 + wn*32 + (nf&1)*16 + llo;
        C[(size_t)(row + j) * N + col] = acc[mf][nf][j] + bias[col];
      }
    }
  }
}

// ---------- fc1 body, f32 inputs (reg-staged convert): 256 threads ----------
// C[fb*128.., 0..128) = input2 @ fc1_w^T + bias, K=768, bf16 out.
// Numerically identical to the bf16-staged path (same RNE convert, same MFMA).
__device__ __forceinline__
void fc1f32_body(char* lds, const float* __restrict__ A, const float* __restrict__ B,
                 const float* __restrict__ bias, unsigned short* __restrict__ Cb, int fb)
{
  unsigned short (*sA)[32] = (unsigned short(*)[32])lds;
  unsigned short (*sB)[32] = (unsigned short(*)[32])(lds + 8192);
  const int tid = threadIdx.x;
  const int wv = tid >> 6, ln = tid & 63;
  const int wr = wv >> 1, wc = wv & 1;
  const int lhi = ln >> 4, llo = ln & 15;
  const int m0 = fb * 128;
  const int N = 128;
  const int srow = tid >> 1, scol = (tid & 1) * 16;
  const float* Ap = A + (size_t)(m0 + srow) * 768 + scol;
  const float* Bp = B + (size_t)srow * 768 + scol;

  f32x4 acc[4][4];
  #pragma unroll
  for (int m = 0; m < 4; ++m)
    #pragma unroll
    for (int n = 0; n < 4; ++n) acc[m][n] = 0.0f;

  #pragma unroll 1
  for (int kt = 0; kt < 768; kt += 32){
    float4 a4[4], b4[4];
    #pragma unroll
    for (int j = 0; j < 4; ++j){
      a4[j] = *reinterpret_cast<const float4*>(Ap + kt + j*4);
      b4[j] = *reinterpret_cast<const float4*>(Bp + kt + j*4);
    }
    *reinterpret_cast<short8*>(&sA[srow][scol])     = pack8(a4[0], a4[1]);
    *reinterpret_cast<short8*>(&sA[srow][scol + 8]) = pack8(a4[2], a4[3]);
    *reinterpret_cast<short8*>(&sB[srow][scol])     = pack8(b4[0], b4[1]);
    *reinterpret_cast<short8*>(&sB[srow][scol + 8]) = pack8(b4[2], b4[3]);
    __syncthreads();

    short8 av[4], bv[4];
    #pragma unroll
    for (int m = 0; m < 4; ++m)
      av[m] = *reinterpret_cast<const short8*>(&sA[wr*64 + m*16 + llo][lhi*8]);
    #pragma unroll
    for (int n = 0; n < 4; ++n)
      bv[n] = *reinterpret_cast<const short8*>(&sB[wc*64 + n*16 + llo][lhi*8]);

    #pragma unroll
    for (int m = 0; m < 4; ++m)
      #pragma unroll
      for (int n = 0; n < 4; ++n)
        mfma16(acc[m][n], bv[n], av[m]);    // SWAPPED: acc = C[m-row][n-cols]
    __syncthreads();
  }

  asm volatile("s_nop 7\n\ts_nop 7\n\ts_nop 7" ::: );

  float4 bias4[4];
  #pragma unroll
  for (int n = 0; n < 4; ++n)
    bias4[n] = *reinterpret_cast<const float4*>(&bias[wc*64 + n*16 + lhi*4]);

  #pragma unroll
  for (int m = 0; m < 4; ++m){
    const int row = m0 + wr*64 + m*16 + llo;
    #pragma unroll
    for (int n = 0; n < 4; ++n){
      const int colbase = wc*64 + n*16 + lhi*4;
      ushort4 o;
      o.x = f2bf(acc[m][n][0] + bias4[n].x);
      o.y = f2bf(acc[m][n][1] + bias4[n].y);
      o.z = f2bf(acc[m][n][2] + bias4[n].z);
      o.w = f2bf(acc[m][n][3] + bias4[n].w);
      *reinterpret_cast<ushort4*>(&Cb[(size_t)row * N + colbase]) = o;
    }
  }
}

// ---------- mean body, f32 input, 256 threads, contiguous reads ----------
__device__ __forceinline__
void meanf32_body(char* lds, const float* __restrict__ input,
                  float* __restrict__ meanb, float* __restrict__ n1p, int mbid)
{
  float (*tmp)[128] = (float(*)[128])lds;   // [16][128] = 8 KB
  const int b = mbid / 6, cg = mbid % 6;
  const int tid = threadIdx.x;
  const int oct = tid & 15, rg = tid >> 4;       // 16 row-groups of 64 rows
  const float* ip = input + (size_t)b*NT*CH + (size_t)rg*64*CH + cg*128 + oct*8;

  float s[8];
  #pragma unroll
  for (int j = 0; j < 8; ++j) s[j] = 0.f;
  #pragma unroll 2
  for (int r = 0; r < 64; ++r){
    float4 v0 = *reinterpret_cast<const float4*>(ip + (size_t)r*CH);
    float4 v1 = *reinterpret_cast<const float4*>(ip + (size_t)r*CH + 4);
    s[0]+=v0.x; s[1]+=v0.y; s[2]+=v0.z; s[3]+=v0.w;
    s[4]+=v1.x; s[5]+=v1.y; s[6]+=v1.z; s[7]+=v1.w;
  }
  #pragma unroll
  for (int j = 0; j < 8; ++j) tmp[rg][oct*8 + j] = s[j];
  __syncthreads();

  if (tid < 128){
    float m = 0.f;
    #pragma unroll
    for (int g = 0; g < 16; ++g) m += tmp[g][tid];
    m *= (1.0f/1024.0f);
    meanb[b*CH + cg*128 + tid] = m;
    float q = m * m;
    for (int off = 32; off; off >>= 1) q += __shfl_down(q, off, 64);
    if ((tid & 63) == 0) n1p[b*12 + cg*2 + (tid >> 6)] = q;
  }
}

// ---------- mega dispatch: fc1 (128) | mean (96) | f2bf convert (2048) ----------
// fc1/mean read f32 inputs directly -> no dependency on the converts.
__global__ void k_mega(const float* __restrict__ input, const float* __restrict__ input2,
                       const float* __restrict__ qkv_w, const float* __restrict__ fc2_w,
                       unsigned short* __restrict__ x1b, unsigned short* __restrict__ xrb,
                       unsigned short* __restrict__ wqb, unsigned short* __restrict__ w2b,
                       const float* __restrict__ fc1_w, const float* __restrict__ fc1_b,
                       unsigned short* __restrict__ t1dst,
                       float* __restrict__ meanb, float* __restrict__ n1p)
{
  __shared__ __align__(64) char lds[16384];
  const int bid = blockIdx.x;
  if (bid < 128){
    fc1f32_body(lds, input2, fc1_w, fc1_b, t1dst, bid);
  } else if (bid < 224){
    meanf32_body(lds, input, meanb, n1p, bid - 128);
  } else {
    // grid-stride f2bf over 4 segments (input, input2, qkv_w, fc2_w)
    const long step = (long)2048 * 256 * 4;
    for (long i = (long)((bid - 224) * 256 + threadIdx.x) * 4; i < 27033600L; i += step){
      const float* s; unsigned short* d; long off;
      if      (i < 12582912L){ s = input;  d = x1b; off = i; }
      else if (i < 25165824L){ s = input2; d = xrb; off = i - 12582912L; }
      else if (i < 26935296L){ s = qkv_w;  d = wqb; off = i - 25165824L; }
      else                   { s = fc2_w;  d = w2b; off = i - 26935296L; }
      float4 v = *reinterpret_cast<const float4*>(s + off);
      ushort4 o;
      o.x = f2bf(v.x); o.y = f2bf(v.y); o.z = f2bf(v.z); o.w = f2bf(v.w);
      *reinterpret_cast<ushort4*>(d + off) = o;
    }
  }
}

// ---------- threefry2x32 (JAX), 20 rounds ----------
__device__ __forceinline__ void threefry(unsigned k0, unsigned k1, unsigned x0, unsigned x1,
                                         unsigned& o0, unsigned& o1){
  unsigned ks2 = k0 ^ k1 ^ 0x1BD11BDAu;
  x0 += k0; x1 += k1;
#define TFR(r) { x0 += x1; x1 = (x1 << r) | (x1 >> (32 - r)); x1 ^= x0; }
  TFR(13) TFR(15) TFR(26) TFR(6)  x0 += k1;  x1 += ks2 + 1u;
  TFR(17) TFR(29) TFR(16) TFR(24) x0 += ks2; x1 += k0 + 2u;
  TFR(13) TFR(15) TFR(26) TFR(6)  x0 += k0;  x1 += k1 + 3u;
  TFR(17) TFR(29) TFR(16) TFR(24) x0 += k1;  x1 += ks2 + 4u;
  TFR(13) TFR(15) TFR(26) TFR(6)  x0 += ks2; x1 += k0 + 5u;
#undef TFR
  o0 = x0; o1 = x1;
}

__device__ __forceinline__ float gumbel_from_bits(unsigned bits){
  float f = __uint_as_float((bits >> 9) | 0x3F800000u) - 1.0f;
  const float TINY = 1.17549435e-38f;
  float u = fmaxf(TINY, f + TINY);
  return -logf(-logf(u));
}

// ---------- router body: 512 threads, 2 tokens each; 1 barrier ----------
__device__ __forceinline__
void router_body(char* lds, const float* __restrict__ part, const float* __restrict__ n1p,
                 const float* __restrict__ r1w, const float* __restrict__ r1b,
                 const float* __restrict__ r2w, const float* __restrict__ r2b,
                 float* __restrict__ out, int b)
{
  float* cs   = (float*)lds;                 // [1024]
  float* red  = (float*)(lds + 4096);        // [16]
  float* w1s  = (float*)(lds + 4096 + 64);   // [128] x4
  float* b1s  = w1s + HIDN;
  float* w20s = b1s + HIDN;
  float* w21s = w20s + HIDN;
  const int tid = threadIdx.x;
  if (tid < HIDN){
    w1s[tid]  = r1w[tid];
    b1s[tid]  = r1b[tid];
    w20s[tid] = r2w[tid];
    w21s[tid] = r2w[HIDN + tid];
  }
  float n1s = 0.f;
  #pragma unroll
  for (int s = 0; s < 12; ++s) n1s += n1p[b*12 + s];
  float n1 = sqrtf(n1s);
  float lmin = 3.4e38f, lmax = -3.4e38f;
  #pragma unroll
  for (int j = 0; j < 2; ++j){
    int tk = tid + j*512;
    int t = b*NT + tk;
    float dot = 0.f, q = 0.f;
    #pragma unroll
    for (int s = 0; s < 12; ++s){
      dot += part[(size_t)s * MTOT + t];
      q   += part[(size_t)(12 + s) * MTOT + t];
    }
    float v = dot / (n1 * sqrtf(q));
    cs[tk] = v;
    lmin = fminf(lmin, v); lmax = fmaxf(lmax, v);
  }
  int ln = tid & 63, wv = tid >> 6;
  for (int off = 32; off; off >>= 1){
    lmin = fminf(lmin, __shfl_down(lmin, off, 64));
    lmax = fmaxf(lmax, __shfl_down(lmax, off, 64));
  }
  if (ln == 0){ red[wv] = lmin; red[8+wv] = lmax; }
  __syncthreads();
  float mn = red[0], mx = red[8];
  #pragma unroll
  for (int s = 1; s < 8; ++s){ mn = fminf(mn, red[s]); mx = fmaxf(mx, red[8+s]); }
  float rng = mx - mn;
  bool nz = (rng != 0.0f);

  const float r2b0 = r2b[0], r2b1 = r2b[1];
  float v[2], l0[2], l1[2];
  #pragma unroll
  for (int j = 0; j < 2; ++j){
    float c0 = cs[tid + j*512];
    v[j] = nz ? (c0 - mn) / rng : c0;
    l0[j] = r2b0; l1[j] = r2b1;
  }
  for (int k = 0; k < HIDN; ++k){
    float a = w1s[k], bb = b1s[k], c0 = w20s[k], c1 = w21s[k];
    #pragma unroll
    for (int j = 0; j < 2; ++j){
      float hh = fmaxf(v[j] * a + bb, 0.f);
      l0[j] += hh * c0;
      l1[j] += hh * c1;
    }
  }
  #pragma unroll
  for (int j = 0; j < 2; ++j){
    float s0 = 1.f / (1.f + expf(-l0[j]));
    float s1 = 1.f / (1.f + expf(-l1[j]));
    int t = b*NT + tid + j*512;
    unsigned o0, o1;
    threefry(0u, 42u, 0u, (unsigned)(2*t),     o0, o1);
    float g0 = gumbel_from_bits(o0 ^ o1);
    threefry(0u, 42u, 0u, (unsigned)(2*t + 1), o0, o1);
    float g1 = gumbel_from_bits(o0 ^ o1);
    out[t] = 1.f / (1.f + expf((s1 + g1) - (s0 + g0)));
  }
}

// ---------- combo 2: combined qkv GEMM (1152) | router (16) ----------
__global__ __launch_bounds__(512, 2)
void k_combo2(const unsigned short* __restrict__ Aall, const unsigned short* __restrict__ wqb,
              const float* __restrict__ qkv_b, float* __restrict__ q1q2,
              const float* __restrict__ part, const float* __restrict__ n1p,
              const float* __restrict__ r1w, const float* __restrict__ r1b,
              const float* __restrict__ r2w, const float* __restrict__ r2b,
              float* __restrict__ router)
{
  __shared__ __align__(1024) char lds8[131072];
  const int bid = blockIdx.x;
  if (bid < 1152){
    gemm256_body<CH/64>(lds8, Aall, wqb, qkv_b, q1q2, OUTF, CH, OUTF/256, bid, 1152);
  } else {
    router_body(lds8, part, n1p, r1w, r1b, r2w, r2b, router, bid - 1152);
  }
}

// ---------- m97-structure MFMA GEMM, fc2 (EPI1): refine + csim partials ----------
__global__ __launch_bounds__(256, 2)
void k_gemm_fc2(const unsigned short* __restrict__ A, const unsigned short* __restrict__ B,
                const float* __restrict__ bias, const unsigned short* __restrict__ addb,
                unsigned short* __restrict__ Cb,
                const float* __restrict__ meanb, float* __restrict__ part,
                int M, int N, int K)
{
  __shared__ unsigned short sA[128][32];
  __shared__ unsigned short sB[128][32];
  const int tid = threadIdx.x;
  const int wv = tid >> 6, ln = tid & 63;
  const int wr = wv >> 1, wc = wv & 1;
  const int lhi = ln >> 4, llo = ln & 15;
  const int m0 = blockIdx.x * 128, n0 = blockIdx.y * 128;

  f32x4 acc[4][4];
  #pragma unroll
  for (int m = 0; m < 4; ++m)
    #pragma unroll
    for (int n = 0; n < 4; ++n) acc[m][n] = 0.0f;

  const int lrow = ln >> 2;
  const int lk8  = (ln & 3) * 8;

  for (int kt = 0; kt < K; kt += 32){
    #pragma unroll
    for (int cc = 0; cc < 2; ++cc){
      int c = wv * 2 + cc;
      gload16(A + (size_t)(m0 + c*16 + lrow) * K + kt + lk8, &sA[c*16][0]);
      gload16(B + (size_t)(n0 + c*16 + lrow) * K + kt + lk8, &sB[c*16][0]);
    }
    __syncthreads();

    short8 av[4], bv[4];
    #pragma unroll
    for (int m = 0; m < 4; ++m)
      av[m] = *reinterpret_cast<const short8*>(&sA[wr*64 + m*16 + llo][lhi*8]);
    #pragma unroll
    for (int n = 0; n < 4; ++n)
      bv[n] = *reinterpret_cast<const short8*>(&sB[wc*64 + n*16 + llo][lhi*8]);

    #pragma unroll
    for (int m = 0; m < 4; ++m)
      #pragma unroll
      for (int n = 0; n < 4; ++n)
        mfma16(acc[m][n], bv[n], av[m]);    // SWAPPED
    __syncthreads();
  }

  asm volatile("s_nop 7\n\ts_nop 7\n\ts_nop 7" ::: );

  float4 bias4[4];
  #pragma unroll
  for (int n = 0; n < 4; ++n)
    bias4[n] = *reinterpret_cast<const float4*>(&bias[n0 + wc*64 + n*16 + lhi*4]);

  const int bb = m0 >> 10;
  const float* mp = meanb + bb * CH;
  float4 mp4[4];
  #pragma unroll
  for (int n = 0; n < 4; ++n)
    mp4[n] = *reinterpret_cast<const float4*>(&mp[n0 + wc*64 + n*16 + lhi*4]);

  #pragma unroll
  for (int m = 0; m < 4; ++m){
    const int row = m0 + wr*64 + m*16 + llo;
    float dsum = 0.f, qsum = 0.f;
    #pragma unroll
    for (int n = 0; n < 4; ++n){
      const int colbase = n0 + wc*64 + n*16 + lhi*4;
      ushort4 a4 = *reinterpret_cast<const ushort4*>(&addb[(size_t)row * N + colbase]);
      float v0 = acc[m][n][0] + bias4[n].x + bf2f(a4.x);
      float v1 = acc[m][n][1] + bias4[n].y + bf2f(a4.y);
      float v2 = acc[m][n][2] + bias4[n].z + bf2f(a4.z);
      float v3 = acc[m][n][3] + bias4[n].w + bf2f(a4.w);
      ushort4 o; o.x = f2bf(v0); o.y = f2bf(v1); o.z = f2bf(v2); o.w = f2bf(v3);
      *reinterpret_cast<ushort4*>(&Cb[(size_t)row * N + colbase]) = o;
      dsum += v0*mp4[n].x + v1*mp4[n].y + v2*mp4[n].z + v3*mp4[n].w;
      qsum += v0*v0 + v1*v1 + v2*v2 + v3*v3;
    }
    dsum += __shfl_xor(dsum, 16, 64);  qsum += __shfl_xor(qsum, 16, 64);
    dsum += __shfl_xor(dsum, 32, 64);  qsum += __shfl_xor(qsum, 32, 64);
    if (ln < 16){
      const int slot = blockIdx.y * 2 + wc;            // 0..11
      part[(size_t)slot * MTOT + row] = dsum;
      part[(size_t)(12 + slot) * MTOT + row] = qsum;
    }
  }
}

// ---------- depthwise 3x3 SAME conv over 32x32 + bias + exact GELU (bf16) ----------
__global__ void k_dwgelu(const unsigned short* __restrict__ t1b, const float* __restrict__ dww,
                         const float* __restrict__ dwb, unsigned short* __restrict__ t2)
{
  int idx = blockIdx.x * blockDim.x + threadIdx.x;
  int hq = idx & 31; int t = idx >> 5;
  int h = hq * 4;
  int n = t & (NT-1); int b = t >> 10;
  int y = n >> 5, x = n & 31;

  float w[4][9];
  #pragma unroll
  for (int i = 0; i < 4; ++i)
    #pragma unroll
    for (int k = 0; k < 9; ++k) w[i][k] = dww[(h+i)*9 + k];

  float a0 = dwb[h+0], a1 = dwb[h+1], a2 = dwb[h+2], a3 = dwb[h+3];
  #pragma unroll
  for (int dy = -1; dy <= 1; ++dy){
    int yy = y + dy; if ((unsigned)yy >= 32u) continue;
    #pragma unroll
    for (int dx = -1; dx <= 1; ++dx){
      int xx = x + dx; if ((unsigned)xx >= 32u) continue;
      ushort4 v = *reinterpret_cast<const ushort4*>(&t1b[((size_t)b*NT + yy*32 + xx)*HIDN + h]);
      int k = (dy+1)*3 + (dx+1);
      a0 += bf2f(v.x) * w[0][k]; a1 += bf2f(v.y) * w[1][k];
      a2 += bf2f(v.z) * w[2][k]; a3 += bf2f(v.w) * w[3][k];
    }
  }
  const float is2 = 0.70710678118654752440f;
  a0 = 0.5f*a0*(1.0f + erff(a0*is2));
  a1 = 0.5f*a1*(1.0f + erff(a1*is2));
  a2 = 0.5f*a2*(1.0f + erff(a2*is2));
  a3 = 0.5f*a3*(1.0f + erff(a3*is2));
  ushort4 o; o.x = f2bf(a0); o.y = f2bf(a1); o.z = f2bf(a2); o.w = f2bf(a3);
  *reinterpret_cast<ushort4*>(&t2[(size_t)t*HIDN + h]) = o;
}

extern "C" void kernel_launch(void* const* d_in, const int* in_sizes, int n_in,
                              void* d_out, int out_size, void* d_ws, size_t ws_size,
                              hipStream_t stream)
{
  (void)in_sizes; (void)n_in; (void)out_size;
  const float* input  = (const float*)d_in[0];
  const float* input2 = (const float*)d_in[3];
  const float* qkv_w  = (const float*)d_in[4];
  const float* qkv_b  = (const float*)d_in[5];
  const float* fc1_w  = (const float*)d_in[6];
  const float* fc1_b  = (const float*)d_in[7];
  const float* dw_w   = (const float*)d_in[8];
  const float* dw_b   = (const float*)d_in[9];
  const float* fc2_w  = (const float*)d_in[10];
  const float* fc2_b  = (const float*)d_in[11];
  const float* r1_w   = (const float*)d_in[12];
  const float* r1_b   = (const float*)d_in[13];
  const float* r2_w   = (const float*)d_in[14];
  const float* r2_b   = (const float*)d_in[15];

  float* q1 = (float*)d_out;
  float* router = q1 + (size_t)2 * MTOT * OUTF;

  if (ws_size < 67000000u) return;

  char* ws = (char*)d_ws;
  unsigned short* x1b = (unsigned short*)ws; ws += (size_t)MTOT*CH*2;   // input bf16   } contiguous:
  unsigned short* xrb = (unsigned short*)ws; ws += (size_t)MTOT*CH*2;   // refine bf16  } A=[x1b;xrb]
  unsigned short* wqb = (unsigned short*)ws; ws += (size_t)OUTF*CH*2;
  ws += (size_t)HIDN*CH*2;                                              // (w1b slot, unused)
  unsigned short* w2b = (unsigned short*)ws; ws += (size_t)CH*HIDN*2;
  unsigned short* t1b = (unsigned short*)ws; ws += (size_t)MTOT*HIDN*4; // 8MB region: part | t1dst
  unsigned short* t2  = (unsigned short*)ws; ws += (size_t)MTOT*HIDN*2;
  float*          mb  = (float*)ws;          ws += (size_t)BQ*CH*4;
  float*          n1p = (float*)ws;          ws += 1024;               // [16][12] partials
  float*          part= (float*)t1b;         // csim partials [24][16384] alias region

  // 1) mega: fc1 (f32-staged, 128 blocks) | mean (f32, 96) | f2bf converts (2048)
  unsigned short* t1dst = t1b + (size_t)MTOT*HIDN;  // upper half of region
  k_mega<<<dim3(2272), 256, 0, stream>>>(
      input, input2, qkv_w, fc2_w, x1b, xrb, wqb, w2b,
      fc1_w, fc1_b, t1dst, mb, n1p);

  // 2) depthwise conv + gelu -> t2 bf16
  k_dwgelu<<<dim3(MTOT*32/256), 256, 0, stream>>>(t1dst, dw_w, dw_b, t2);

  // 3) fc2 + input2(bf16) add -> refine bf16 (into xrb) + csim partials -> part
  k_gemm_fc2<<<dim3(MTOT/128, CH/128), 256, 0, stream>>>(
      t2, w2b, fc2_b, xrb, xrb, mb, part, MTOT, CH, HIDN);

  // 4) combo2: combined qkv [q1;q2] GEMM (1152 blocks) | router (16)
  k_combo2<<<dim3(1168), 512, 0, stream>>>(
      x1b, wqb, qkv_b, q1, part, n1p, r1_w, r1_b, r2_w, r2_b, router);
}